// Round 1
// baseline (124.050 us; speedup 1.0000x reference)
//
#include <hip/hip_runtime.h>

#define FEA 128  // features per atom (128 floats = 32 float4)

// One wave (64 lanes) per segment. segment_ids is sorted, so each segment is a
// contiguous run of atoms; each wave binary-searches its [start,end) range and
// streams the run with float4 loads (16 B/lane), 2 atoms per wave-iteration.
__global__ __launch_bounds__(256) void segmean_kernel(
    const float* __restrict__ atom_fea,   // (N, 128) f32
    const int*   __restrict__ ids,        // (N,) sorted int32
    float*       __restrict__ out,        // (N0, 128) f32
    int n_atoms, int n_seg)
{
    const int wave = threadIdx.x >> 6;
    const int lane = threadIdx.x & 63;
    const int seg  = blockIdx.x * 4 + wave;
    if (seg >= n_seg) return;

    // Dual uniform binary search (all lanes identical -> broadcast loads):
    // lo0 = lower_bound(ids, seg), lo1 = lower_bound(ids, seg+1)
    int lo0 = 0, hi0 = n_atoms;
    int lo1 = 0, hi1 = n_atoms;
    while ((lo0 < hi0) | (lo1 < hi1)) {
        if (lo0 < hi0) {
            int mid = (lo0 + hi0) >> 1;
            if (ids[mid] < seg) lo0 = mid + 1; else hi0 = mid;
        }
        if (lo1 < hi1) {
            int mid = (lo1 + hi1) >> 1;
            if (ids[mid] < seg + 1) lo1 = mid + 1; else hi1 = mid;
        }
    }
    const int start = lo0;
    const int n     = lo1 - lo0;   // atoms in this segment (may be 0)

    // Lane layout: a_sub in {0,1} picks which of 2 concurrent atoms,
    // g in [0,32) picks the float4 (features 4g..4g+3).
    const int a_sub = lane >> 5;
    const int g     = lane & 31;

    const float4* base = (const float4*)atom_fea + (size_t)start * 32 + g;

    float4 acc0 = make_float4(0.f, 0.f, 0.f, 0.f);
    float4 acc1 = make_float4(0.f, 0.f, 0.f, 0.f);

    int k = a_sub;
    // Unrolled x2: two independent loads in flight per thread (atoms k, k+2).
    for (; k + 2 < n; k += 4) {
        float4 v0 = base[(size_t)k       * 32];
        float4 v1 = base[(size_t)(k + 2) * 32];
        acc0.x += v0.x; acc0.y += v0.y; acc0.z += v0.z; acc0.w += v0.w;
        acc1.x += v1.x; acc1.y += v1.y; acc1.z += v1.z; acc1.w += v1.w;
    }
    for (; k < n; k += 2) {
        float4 v = base[(size_t)k * 32];
        acc0.x += v.x; acc0.y += v.y; acc0.z += v.z; acc0.w += v.w;
    }

    acc0.x += acc1.x; acc0.y += acc1.y; acc0.z += acc1.z; acc0.w += acc1.w;

    // Combine the two half-wave partials (a_sub=0 holds atoms 0,4,..; a_sub=1 holds 1,5,..).
    acc0.x += __shfl_xor(acc0.x, 32, 64);
    acc0.y += __shfl_xor(acc0.y, 32, 64);
    acc0.z += __shfl_xor(acc0.z, 32, 64);
    acc0.w += __shfl_xor(acc0.w, 32, 64);

    const float invn = 1.0f / (float)((n > 0) ? n : 1);  // empty-segment guard (== max(counts,1))

    if (a_sub == 0) {
        float4 r;
        r.x = acc0.x * invn; r.y = acc0.y * invn;
        r.z = acc0.z * invn; r.w = acc0.w * invn;
        ((float4*)out)[(size_t)seg * 32 + g] = r;
    }
}

extern "C" void kernel_launch(void* const* d_in, const int* in_sizes, int n_in,
                              void* d_out, int out_size, void* d_ws, size_t ws_size,
                              hipStream_t stream) {
    const float* atom_fea = (const float*)d_in[0];
    const int*   ids      = (const int*)d_in[1];
    float*       out      = (float*)d_out;

    const int n_atoms = in_sizes[1];        // N (ids length)
    const int n_seg   = out_size / FEA;     // N0

    const int blocks = (n_seg + 3) / 4;     // 4 waves (segments) per block
    segmean_kernel<<<blocks, 256, 0, stream>>>(atom_fea, ids, out, n_atoms, n_seg);
}

// Round 2
// 109.750 us; speedup vs baseline: 1.1303x; 1.1303x over previous
//
#include <hip/hip_runtime.h>

#define FEA 128  // features per atom (128 floats = 32 float4)

// ---------------------------------------------------------------------------
// Kernel A: build segment boundaries B[s] = lower_bound(ids, s), s in [0, n_seg].
// ids is sorted, so each thread scans 4 consecutive ids and scatters boundary
// indices wherever the id changes. Every B[s] is written exactly once.
// ---------------------------------------------------------------------------
__global__ __launch_bounds__(256) void build_bounds_kernel(
    const int* __restrict__ ids, int* __restrict__ B, int n_atoms, int n_seg)
{
    const int t  = blockIdx.x * blockDim.x + threadIdx.x;
    const int i0 = t * 4;
    if (i0 >= n_atoms) return;

    int prev = (i0 == 0) ? -1 : ids[i0 - 1];

    if (i0 + 3 < n_atoms) {
        const int4 v = *(const int4*)(ids + i0);
        const int cur[4] = {v.x, v.y, v.z, v.w};
        #pragma unroll
        for (int j = 0; j < 4; ++j) {
            if (cur[j] != prev)
                for (int s = prev + 1; s <= cur[j]; ++s) B[s] = i0 + j;
            prev = cur[j];
        }
        if (i0 + 4 == n_atoms)
            for (int s = prev + 1; s <= n_seg; ++s) B[s] = n_atoms;
    } else {
        for (int j = 0; j < 4 && i0 + j < n_atoms; ++j) {
            const int c = ids[i0 + j];
            if (c != prev)
                for (int s = prev + 1; s <= c; ++s) B[s] = i0 + j;
            prev = c;
        }
        if (i0 + 4 >= n_atoms)
            for (int s = prev + 1; s <= n_seg; ++s) B[s] = n_atoms;
    }
}

// ---------------------------------------------------------------------------
// Kernel B: one wave (64 lanes) per segment, range from precomputed B[].
// Lane layout: a_sub in {0,1} picks which of 2 concurrent atoms, g in [0,32)
// picks the float4. 4-deep unroll -> 4 loads (4 KB/wave-iter) in flight.
// ---------------------------------------------------------------------------
__global__ __launch_bounds__(256) void segmean_kernel(
    const float* __restrict__ atom_fea,
    const int*   __restrict__ B,
    float*       __restrict__ out,
    int n_seg)
{
    const int wave = threadIdx.x >> 6;
    const int lane = threadIdx.x & 63;
    const int seg  = blockIdx.x * 4 + wave;
    if (seg >= n_seg) return;

    const int start = B[seg];
    const int n     = B[seg + 1] - start;

    const int a_sub = lane >> 5;
    const int g     = lane & 31;

    const float4* base = (const float4*)atom_fea + (size_t)start * 32 + g;

    float4 a0 = make_float4(0.f, 0.f, 0.f, 0.f);
    float4 a1 = make_float4(0.f, 0.f, 0.f, 0.f);
    float4 a2 = make_float4(0.f, 0.f, 0.f, 0.f);
    float4 a3 = make_float4(0.f, 0.f, 0.f, 0.f);

    int k = a_sub;
    for (; k + 6 < n; k += 8) {
        float4 v0 = base[(size_t)k       * 32];
        float4 v1 = base[(size_t)(k + 2) * 32];
        float4 v2 = base[(size_t)(k + 4) * 32];
        float4 v3 = base[(size_t)(k + 6) * 32];
        a0.x += v0.x; a0.y += v0.y; a0.z += v0.z; a0.w += v0.w;
        a1.x += v1.x; a1.y += v1.y; a1.z += v1.z; a1.w += v1.w;
        a2.x += v2.x; a2.y += v2.y; a2.z += v2.z; a2.w += v2.w;
        a3.x += v3.x; a3.y += v3.y; a3.z += v3.z; a3.w += v3.w;
    }
    for (; k < n; k += 2) {
        float4 v = base[(size_t)k * 32];
        a0.x += v.x; a0.y += v.y; a0.z += v.z; a0.w += v.w;
    }

    a0.x += a1.x + a2.x + a3.x;
    a0.y += a1.y + a2.y + a3.y;
    a0.z += a1.z + a2.z + a3.z;
    a0.w += a1.w + a2.w + a3.w;

    a0.x += __shfl_xor(a0.x, 32, 64);
    a0.y += __shfl_xor(a0.y, 32, 64);
    a0.z += __shfl_xor(a0.z, 32, 64);
    a0.w += __shfl_xor(a0.w, 32, 64);

    const float invn = 1.0f / (float)((n > 0) ? n : 1);  // empty-segment guard

    if (a_sub == 0) {
        float4 r;
        r.x = a0.x * invn; r.y = a0.y * invn;
        r.z = a0.z * invn; r.w = a0.w * invn;
        ((float4*)out)[(size_t)seg * 32 + g] = r;
    }
}

// ---------------------------------------------------------------------------
// Fallback (ws too small): original binary-search variant, kept for safety.
// ---------------------------------------------------------------------------
__global__ __launch_bounds__(256) void segmean_bsearch_kernel(
    const float* __restrict__ atom_fea,
    const int*   __restrict__ ids,
    float*       __restrict__ out,
    int n_atoms, int n_seg)
{
    const int wave = threadIdx.x >> 6;
    const int lane = threadIdx.x & 63;
    const int seg  = blockIdx.x * 4 + wave;
    if (seg >= n_seg) return;

    int lo0 = 0, hi0 = n_atoms, lo1 = 0, hi1 = n_atoms;
    while ((lo0 < hi0) | (lo1 < hi1)) {
        if (lo0 < hi0) { int m = (lo0 + hi0) >> 1; if (ids[m] < seg)     lo0 = m + 1; else hi0 = m; }
        if (lo1 < hi1) { int m = (lo1 + hi1) >> 1; if (ids[m] < seg + 1) lo1 = m + 1; else hi1 = m; }
    }
    const int start = lo0;
    const int n     = lo1 - lo0;

    const int a_sub = lane >> 5;
    const int g     = lane & 31;
    const float4* base = (const float4*)atom_fea + (size_t)start * 32 + g;

    float4 a0 = make_float4(0.f, 0.f, 0.f, 0.f);
    for (int k = a_sub; k < n; k += 2) {
        float4 v = base[(size_t)k * 32];
        a0.x += v.x; a0.y += v.y; a0.z += v.z; a0.w += v.w;
    }
    a0.x += __shfl_xor(a0.x, 32, 64);
    a0.y += __shfl_xor(a0.y, 32, 64);
    a0.z += __shfl_xor(a0.z, 32, 64);
    a0.w += __shfl_xor(a0.w, 32, 64);

    const float invn = 1.0f / (float)((n > 0) ? n : 1);
    if (a_sub == 0) {
        float4 r;
        r.x = a0.x * invn; r.y = a0.y * invn;
        r.z = a0.z * invn; r.w = a0.w * invn;
        ((float4*)out)[(size_t)seg * 32 + g] = r;
    }
}

extern "C" void kernel_launch(void* const* d_in, const int* in_sizes, int n_in,
                              void* d_out, int out_size, void* d_ws, size_t ws_size,
                              hipStream_t stream) {
    const float* atom_fea = (const float*)d_in[0];
    const int*   ids      = (const int*)d_in[1];
    float*       out      = (float*)d_out;

    const int n_atoms = in_sizes[1];
    const int n_seg   = out_size / FEA;

    const size_t bounds_bytes = (size_t)(n_seg + 1) * sizeof(int);
    const int    seg_blocks   = (n_seg + 3) / 4;   // 4 waves (segments) per block

    if (ws_size >= bounds_bytes) {
        int* B = (int*)d_ws;
        const int n_thr    = (n_atoms + 3) / 4;
        const int b_blocks = (n_thr + 255) / 256;
        build_bounds_kernel<<<b_blocks, 256, 0, stream>>>(ids, B, n_atoms, n_seg);
        segmean_kernel<<<seg_blocks, 256, 0, stream>>>(atom_fea, B, out, n_seg);
    } else {
        segmean_bsearch_kernel<<<seg_blocks, 256, 0, stream>>>(atom_fea, ids, out, n_atoms, n_seg);
    }
}

// Round 3
// 109.274 us; speedup vs baseline: 1.1352x; 1.0044x over previous
//
#include <hip/hip_runtime.h>

#define FEA   128   // floats per atom row (512 B)
#define CHUNK 128   // atoms per wave (64 KB contiguous stream per wave)

typedef float f4 __attribute__((ext_vector_type(4)));

// ---------------------------------------------------------------------------
// Prologue (one launch, two thread roles by blockIdx):
//  role A: build B[s] = lower_bound(ids, s) for s in [0, n_seg]; zero rows of
//          empty segments (B[s]==B[s+1]).
//  role B: for each chunk boundary p = k*CHUNK, if ids[p-1]==ids[p] the
//          segment straddles the boundary -> zero its output row (it will be
//          accumulated via atomicAdd by the main kernel).
// ---------------------------------------------------------------------------
__global__ __launch_bounds__(256) void prologue_kernel(
    const int* __restrict__ ids, int* __restrict__ B, float* __restrict__ out,
    int n_atoms, int n_seg, int b_blocks, int n_chunks)
{
    if ((int)blockIdx.x < b_blocks) {
        // ---- role A: bounds + empty rows ----
        const int t  = blockIdx.x * 256 + threadIdx.x;
        const int i0 = t * 4;
        if (i0 >= n_atoms) return;
        int prev = (i0 == 0) ? -1 : ids[i0 - 1];
        #pragma unroll
        for (int j = 0; j < 4; ++j) {
            const int i = i0 + j;
            if (i >= n_atoms) break;
            const int cur = ids[i];
            if (cur != prev) {
                for (int s = prev + 1; s <= cur; ++s) B[s] = i;
                for (int s = prev + 1; s < cur; ++s) {        // empty segments
                    f4* row = (f4*)(out + (size_t)s * FEA);
                    const f4 z = {0.f, 0.f, 0.f, 0.f};
                    for (int q = 0; q < FEA / 4; ++q) row[q] = z;
                }
                prev = cur;
            }
        }
        if (i0 + 4 >= n_atoms) {
            for (int s = prev + 1; s <= n_seg; ++s) B[s] = n_atoms;
            for (int s = prev + 1; s < n_seg; ++s) {          // trailing empties
                f4* row = (f4*)(out + (size_t)s * FEA);
                const f4 z = {0.f, 0.f, 0.f, 0.f};
                for (int q = 0; q < FEA / 4; ++q) row[q] = z;
            }
        }
    } else {
        // ---- role B: zero straddler rows (32 lanes per boundary, coalesced) ----
        const int t = ((int)blockIdx.x - b_blocks) * 256 + threadIdx.x;
        const int b = t >> 5;          // boundary index
        const int g = t & 31;
        const int p = (b + 1) * CHUNK;
        if (b >= n_chunks - 1 || p >= n_atoms) return;
        const int sl = ids[p - 1];
        const int sr = ids[p];
        if (sl == sr) {
            const f4 z = {0.f, 0.f, 0.f, 0.f};
            ((f4*)(out + (size_t)sr * FEA))[g] = z;
        }
    }
}

// ---------------------------------------------------------------------------
// Main: one wave per fixed 128-atom chunk (perfectly balanced; 8192 waves =
// exactly one full residency round). Walk the segments overlapping the chunk
// using B[]; interior segments -> direct mean write; straddlers -> pre-divided
// atomicAdd into the zeroed row. Lane layout: a_sub in {0,1} picks which of 2
// concurrent atoms, g in [0,32) picks the float4 (1 KB per wave-instruction).
// ---------------------------------------------------------------------------
__global__ __launch_bounds__(256) void segmean_chunk_kernel(
    const float* __restrict__ atom_fea,
    const int*   __restrict__ ids,
    const int*   __restrict__ B,
    float*       __restrict__ out,
    int n_atoms)
{
    const int wid   = (blockIdx.x * 256 + threadIdx.x) >> 6;
    const int lane  = threadIdx.x & 63;
    const int c0    = wid * CHUNK;
    if (c0 >= n_atoms) return;
    const int c1    = min(c0 + CHUNK, n_atoms);
    const int a_sub = lane >> 5;
    const int g     = lane & 31;

    int s   = ids[c0];    // segment containing the chunk's first atom
    int pos = c0;

    while (pos < c1) {
        const int segS = B[s];
        const int segE = B[s + 1];
        const int e    = min(segE, c1);
        const int m    = e - pos;            // atoms of segment s in this chunk

        const f4* base = (const f4*)atom_fea + (size_t)pos * (FEA / 4) + g;

        f4 a0 = {0.f, 0.f, 0.f, 0.f};
        f4 a1 = {0.f, 0.f, 0.f, 0.f};
        f4 a2 = {0.f, 0.f, 0.f, 0.f};
        f4 a3 = {0.f, 0.f, 0.f, 0.f};

        int k = a_sub;
        for (; k + 6 < m; k += 8) {          // 4 nt loads in flight (4 KB/wave-iter)
            f4 v0 = __builtin_nontemporal_load(base + (size_t)k       * 32);
            f4 v1 = __builtin_nontemporal_load(base + (size_t)(k + 2) * 32);
            f4 v2 = __builtin_nontemporal_load(base + (size_t)(k + 4) * 32);
            f4 v3 = __builtin_nontemporal_load(base + (size_t)(k + 6) * 32);
            a0 += v0; a1 += v1; a2 += v2; a3 += v3;
        }
        for (; k < m; k += 2)
            a0 += __builtin_nontemporal_load(base + (size_t)k * 32);

        a0 += a1 + a2 + a3;

        a0[0] += __shfl_xor(a0[0], 32, 64);
        a0[1] += __shfl_xor(a0[1], 32, 64);
        a0[2] += __shfl_xor(a0[2], 32, 64);
        a0[3] += __shfl_xor(a0[3], 32, 64);

        const int   n_total = segE - segS;
        const float invn    = 1.0f / (float)((n_total > 0) ? n_total : 1);

        if (segS >= c0 && segE <= c1) {
            // interior (or empty) segment: exclusive owner -> direct write
            if (a_sub == 0) {
                f4 r = a0 * invn;
                ((f4*)(out + (size_t)s * FEA))[g] = r;
            }
        } else {
            // straddler: row was zeroed in prologue -> pre-divided atomic add
            if (a_sub == 0) {
                float* dst = out + (size_t)s * FEA + g * 4;
                atomicAdd(dst + 0, a0[0] * invn);
                atomicAdd(dst + 1, a0[1] * invn);
                atomicAdd(dst + 2, a0[2] * invn);
                atomicAdd(dst + 3, a0[3] * invn);
            }
        }
        pos = e;
        ++s;
    }
}

// ---------------------------------------------------------------------------
// Fallback (ws too small): binary-search wave-per-segment variant.
// ---------------------------------------------------------------------------
__global__ __launch_bounds__(256) void segmean_bsearch_kernel(
    const float* __restrict__ atom_fea,
    const int*   __restrict__ ids,
    float*       __restrict__ out,
    int n_atoms, int n_seg)
{
    const int wave = threadIdx.x >> 6;
    const int lane = threadIdx.x & 63;
    const int seg  = blockIdx.x * 4 + wave;
    if (seg >= n_seg) return;

    int lo0 = 0, hi0 = n_atoms, lo1 = 0, hi1 = n_atoms;
    while ((lo0 < hi0) | (lo1 < hi1)) {
        if (lo0 < hi0) { int m = (lo0 + hi0) >> 1; if (ids[m] < seg)     lo0 = m + 1; else hi0 = m; }
        if (lo1 < hi1) { int m = (lo1 + hi1) >> 1; if (ids[m] < seg + 1) lo1 = m + 1; else hi1 = m; }
    }
    const int start = lo0;
    const int n     = lo1 - lo0;

    const int a_sub = lane >> 5;
    const int g     = lane & 31;
    const f4* base  = (const f4*)atom_fea + (size_t)start * (FEA / 4) + g;

    f4 a0 = {0.f, 0.f, 0.f, 0.f};
    for (int k = a_sub; k < n; k += 2)
        a0 += *(base + (size_t)k * 32);

    a0[0] += __shfl_xor(a0[0], 32, 64);
    a0[1] += __shfl_xor(a0[1], 32, 64);
    a0[2] += __shfl_xor(a0[2], 32, 64);
    a0[3] += __shfl_xor(a0[3], 32, 64);

    const float invn = 1.0f / (float)((n > 0) ? n : 1);
    if (a_sub == 0) {
        f4 r = a0 * invn;
        ((f4*)(out + (size_t)seg * FEA))[g] = r;
    }
}

extern "C" void kernel_launch(void* const* d_in, const int* in_sizes, int n_in,
                              void* d_out, int out_size, void* d_ws, size_t ws_size,
                              hipStream_t stream) {
    const float* atom_fea = (const float*)d_in[0];
    const int*   ids      = (const int*)d_in[1];
    float*       out      = (float*)d_out;

    const int n_atoms = in_sizes[1];
    const int n_seg   = out_size / FEA;

    const size_t bounds_bytes = (size_t)(n_seg + 1) * sizeof(int);

    if (ws_size >= bounds_bytes) {
        int* B = (int*)d_ws;

        const int n_chunks = (n_atoms + CHUNK - 1) / CHUNK;
        const int b_blocks = (((n_atoms + 3) / 4) + 255) / 256;
        const int z_thr    = (n_chunks > 1) ? (n_chunks - 1) * 32 : 0;
        const int z_blocks = (z_thr + 255) / 256;

        prologue_kernel<<<b_blocks + z_blocks, 256, 0, stream>>>(
            ids, B, out, n_atoms, n_seg, b_blocks, n_chunks);

        const int m_blocks = (n_chunks + 3) / 4;   // 4 waves (chunks) per block
        segmean_chunk_kernel<<<m_blocks, 256, 0, stream>>>(
            atom_fea, ids, B, out, n_atoms);
    } else {
        const int seg_blocks = (n_seg + 3) / 4;
        segmean_bsearch_kernel<<<seg_blocks, 256, 0, stream>>>(
            atom_fea, ids, out, n_atoms, n_seg);
    }
}